// Round 7
// baseline (1239.102 us; speedup 1.0000x reference)
//
#include <hip/hip_runtime.h>
#include <cstdint>
#include <cstddef>

#define RANGE    128       // nodes per fine bucket
#define RSHIFT   7
#define MAXBUCK  800       // >= ceil(N/RANGE); N=100K -> 782
#define CSHIFT   12        // nodes per coarse bucket = 4096
#define CRANGE   4096
#define MAXC     32        // >= ceil(N/CRANGE); N=100K -> 25
#define FPB      32        // fine buckets per coarse bucket
#define CH_CNT   8192      // edges per block, count pass
#define CH_SC    4096      // edges per block, scatter passes
#define EPT      16        // CH_SC / 256
#define PAD      16        // pad global counters to one 64B line each
#define WSTR     132       // LDS stride for transposed W1 (16B-aligned, rotates banks)
#define ACHUNK   4096      // scatter-agg staged chunk, records (32 KB LDS)

typedef _Float16 h8 __attribute__((ext_vector_type(8)));

// DMA a 16B-per-lane chunk global->LDS. lds byte base must be wave-uniform;
// HW writes lds_base + lane*16; global src is per-lane.
#define GLOAD_LDS16(gsrc, ldsb)                                                   \
    __builtin_amdgcn_global_load_lds(                                             \
        (const __attribute__((address_space(1))) uint32_t*)(gsrc),                \
        (__attribute__((address_space(3))) uint32_t*)(ldsb), 16, 0, 0)

// ---------------------------------------------------------------------------
__global__ void zero_pad_kernel(int* __restrict__ p, int n) {
    int i = blockIdx.x * blockDim.x + threadIdx.x;
    if (i < n) p[i * PAD] = 0;
}

// fine histogram (782 buckets) of col>>7; per-block LDS, merged w/ global atomics
__global__ void count_kernel(const int* __restrict__ col, int* __restrict__ fcnt,
                             int nfine, int E) {
    __shared__ int lcnt[MAXBUCK];
    int tid = threadIdx.x;
    for (int i = tid; i < nfine; i += blockDim.x) lcnt[i] = 0;
    __syncthreads();
    int base = blockIdx.x * CH_CNT;
    int end  = min(E, base + CH_CNT);
    for (int e = base + tid; e < end; e += blockDim.x)
        atomicAdd(&lcnt[col[e] >> RSHIFT], 1);
    __syncthreads();
    for (int i = tid; i < nfine; i += blockDim.x)
        if (lcnt[i]) atomicAdd(&fcnt[i * PAD], lcnt[i]);
}

// scan fine counts -> fine bases/cursors; derive coarse bases/cursors
// (row_ptr removed in R6: no pull-mode consumer remains)
__global__ void scan_kernel(const int* __restrict__ fcnt, int* __restrict__ fbase,
                            int* __restrict__ fcur, int* __restrict__ cbase,
                            int* __restrict__ ccur, int nfine, int ncoarse, int E) {
    __shared__ int lds[1024];
    int T = threadIdx.x;
    int s = (T < nfine) ? fcnt[T * PAD] : 0;
    lds[T] = s;
    __syncthreads();
    for (int off = 1; off < 1024; off <<= 1) {
        int v = (T >= off) ? lds[T - off] : 0;
        __syncthreads();
        lds[T] += v;
        __syncthreads();
    }
    int excl = lds[T] - s;
    if (T < nfine) { fbase[T] = excl; fcur[T * PAD] = excl; }
    if ((T & (FPB - 1)) == 0 && (T >> 5) < ncoarse) {
        cbase[T >> 5] = excl;
        ccur[(T >> 5) * PAD] = excl;
    }
    if (T == 0) { fbase[nfine] = E; cbase[ncoarse] = E; }
}

// coarse scatter with LDS counting-sort staging: records leave the block
// bucket-sorted, so global stores are fully coalesced dense segments.
// record = {row | col_low12<<17, ew}
__global__ void coarse_scatter_kernel(const int* __restrict__ row, const int* __restrict__ col,
                                      const float* __restrict__ ew, int* __restrict__ ccur,
                                      uint2* __restrict__ partA, int ncoarse, int E) {
    __shared__ uint2 stage[CH_SC];
    __shared__ unsigned char sb[CH_SC];
    __shared__ int lcnt[MAXC], lofs[MAXC], gofs[MAXC];
    __shared__ int total_s;
    int tid = threadIdx.x;
    if (tid < MAXC) lcnt[tid] = 0;
    __syncthreads();
    int base = blockIdx.x * CH_SC;
    int cnt  = min(E - base, CH_SC);

    uint2 rec[EPT]; int rnk[EPT]; int bb[EPT];
#pragma unroll
    for (int k = 0; k < EPT; k++) {
        int idx = tid + (k << 8);
        if (idx < cnt) {
            int e = base + idx;
            int c = col[e];
            int b = c >> CSHIFT;
            bb[k]  = b;
            rec[k] = make_uint2((unsigned)row[e] | ((unsigned)(c & (CRANGE - 1)) << 17),
                                __float_as_uint(ew[e]));
            rnk[k] = atomicAdd(&lcnt[b], 1);   // one LDS atomic per edge; rank kept in regs
        }
    }
    __syncthreads();
    if (tid == 0) {  // 25-entry serial scan
        int run = 0;
        for (int i = 0; i < ncoarse; i++) { lofs[i] = run; run += lcnt[i]; }
        total_s = run;
    }
    __syncthreads();
    if (tid < ncoarse) {
        int c = lcnt[tid];
        if (c) {
            int g = atomicAdd(&ccur[tid * PAD], c);
            gofs[tid] = g - lofs[tid];
        }
    }
#pragma unroll
    for (int k = 0; k < EPT; k++) {
        int idx = tid + (k << 8);
        if (idx < cnt) {
            int p = lofs[bb[k]] + rnk[k];
            stage[p] = rec[k];
            sb[p] = (unsigned char)bb[k];
        }
    }
    __syncthreads();
    int total = total_s;
    for (int i = tid; i < total; i += 256)   // dense, coalesced copy-out
        partA[gofs[sb[i]] + i] = stage[i];
}

// fine scatter (same staging scheme): partA (coarsely sorted) -> partB grouped
// by 128-node fine bucket.  output record = {row | dst_local<<17, ew}
__global__ __launch_bounds__(256, 3)
void fine_scatter_kernel(const uint2* __restrict__ partA, const int* __restrict__ cbase,
                                    int* __restrict__ fcur, uint2* __restrict__ partB,
                                    int nfine, int ncoarse, int E) {
    __shared__ uint2 stage[CH_SC];
    __shared__ unsigned short sb[CH_SC];
    __shared__ int lcnt[MAXBUCK], lofs[MAXBUCK], gofs[MAXBUCK];
    __shared__ int tmp[256];
    __shared__ int scb[MAXC + 1];
    __shared__ int rlo_s, total_s;
    int tid = threadIdx.x;
    int base = blockIdx.x * CH_SC;
    int cnt  = min(E - base, CH_SC);
    if (tid <= ncoarse) scb[tid] = cbase[tid];
    for (int i = tid; i < nfine; i += 256) lcnt[i] = 0;
    if (tid == 0) {
        int r = 0;
        while (r < ncoarse - 1 && cbase[r + 1] <= base) ++r;
        rlo_s = r;
    }
    __syncthreads();
    int rlo = rlo_s;

    uint2 rec[EPT]; int rnk[EPT]; int ff[EPT];
#pragma unroll
    for (int k = 0; k < EPT; k++) {
        int idx = tid + (k << 8);
        if (idx < cnt) {
            int e = base + idx;
            uint2 v = partA[e];
            int r = rlo;
            while (e >= scb[r + 1]) ++r;   // short walk: chunk spans ~2 regions
            int col12 = (int)((v.x >> 17) & (CRANGE - 1));
            int f = (r << 5) | (col12 >> RSHIFT);
            ff[k]  = f;
            rec[k] = make_uint2((v.x & 0x1FFFFu) | ((unsigned)(col12 & (RANGE - 1)) << 17), v.y);
            rnk[k] = atomicAdd(&lcnt[f], 1);
        }
    }
    __syncthreads();
    {   // parallel exclusive scan of lcnt[0..nfine) -> lofs
        const int Cc = (nfine + 255) >> 8;   // 4 counters per thread
        int b0 = tid * Cc;
        int s = 0;
        for (int i = 0; i < Cc; i++) {
            int idx = b0 + i;
            if (idx < nfine) s += lcnt[idx];
        }
        tmp[tid] = s;
        __syncthreads();
        for (int off = 1; off < 256; off <<= 1) {
            int v = (tid >= off) ? tmp[tid - off] : 0;
            __syncthreads();
            tmp[tid] += v;
            __syncthreads();
        }
        int run = tmp[tid] - s;
        for (int i = 0; i < Cc; i++) {
            int idx = b0 + i;
            if (idx < nfine) { lofs[idx] = run; run += lcnt[idx]; }
        }
        if (tid == 255) total_s = tmp[255];
    }
    __syncthreads();
    for (int i = tid; i < nfine; i += 256) {
        int c = lcnt[i];
        if (c) {
            int g = atomicAdd(&fcur[i * PAD], c);
            gofs[i] = g - lofs[i];
        }
    }
#pragma unroll
    for (int k = 0; k < EPT; k++) {
        int idx = tid + (k << 8);
        if (idx < cnt) {
            int p = lofs[ff[k]] + rnk[k];
            stage[p] = rec[k];
            sb[p] = (unsigned short)ff[k];
        }
    }
    __syncthreads();
    int total = total_s;
    for (int i = tid; i < total; i += 256)   // dense, coalesced copy-out
        partB[gofs[sb[i]] + i] = stage[i];
}

// per-bucket degree only (R6: replaces bucket_csr's sort entirely).
// One float atomic per record into sdeg[128]; tiny LDS -> max occupancy.
__global__ __launch_bounds__(512)
void deg_kernel(const uint2* __restrict__ partB, const int* __restrict__ fbase,
                float* __restrict__ dis, int N) {
    __shared__ float sdeg[RANGE];
    int b = blockIdx.x, tid = threadIdx.x;
    int s = fbase[b], t = fbase[b + 1];
    if (tid < RANGE) sdeg[tid] = 1.0f;   // self-loop weight
    __syncthreads();
    for (int e = s + tid; e < t; e += 512) {
        uint2 r = partB[e];
        atomicAdd(&sdeg[(r.x >> 17) & (RANGE - 1)], __uint_as_float(r.y));
    }
    __syncthreads();
    if (tid < RANGE) {
        int node = b * RANGE + tid;
        if (node < N) dis[node] = rsqrtf(sdeg[tid]);
    }
}

// t1 = fp16(X @ W1) + packed dis.  8 lanes per node: each lane owns 16 of the
// 128 inputs (4 coalesced float4 loads), W1 transposed in LDS (stride 132),
// 192 independent FMAs per lane, then 3-step shuffle reduction.
__global__ void lin1_kernel(const float* __restrict__ X, const float* __restrict__ W1,
                            const float* __restrict__ dis, uint4* __restrict__ t1, int n) {
    __shared__ float w1t[12 * WSTR];
    int tid = threadIdx.x;
    for (int i = tid; i < 128 * 12; i += 256) {
        int k = i / 12, o = i - k * 12;
        w1t[o * WSTR + k] = W1[i];
    }
    __syncthreads();
    int gt   = blockIdx.x * 256 + tid;
    int node = gt >> 3;
    int sub  = gt & 7;
    if (node >= n) return;

    const float4* xp = (const float4*)(X + (size_t)node * 128 + sub * 16);
    float4 x0 = xp[0], x1 = xp[1], x2 = xp[2], x3 = xp[3];

    float res[12];
#pragma unroll
    for (int o = 0; o < 12; o++) {
        const float4* wp = (const float4*)(w1t + o * WSTR + sub * 16);
        float4 w0 = wp[0], w1v = wp[1], w2 = wp[2], w3 = wp[3];
        float s;
        s  = x0.x * w0.x + x0.y * w0.y + x0.z * w0.z + x0.w * w0.w;
        s += x1.x * w1v.x + x1.y * w1v.y + x1.z * w1v.z + x1.w * w1v.w;
        s += x2.x * w2.x + x2.y * w2.y + x2.z * w2.z + x2.w * w2.w;
        s += x3.x * w3.x + x3.y * w3.y + x3.z * w3.z + x3.w * w3.w;
        res[o] = s;
    }
#pragma unroll
    for (int o = 0; o < 12; o++) {
        res[o] += __shfl_xor(res[o], 1, 64);
        res[o] += __shfl_xor(res[o], 2, 64);
        res[o] += __shfl_xor(res[o], 4, 64);
    }
    if (sub == 0) {
        h8 a, b;
#pragma unroll
        for (int o = 0; o < 8; o++) a[o] = (_Float16)res[o];
#pragma unroll
        for (int o = 0; o < 4; o++) b[o] = (_Float16)res[8 + o];
#pragma unroll
        for (int o = 4; o < 8; o++) b[o] = (_Float16)0.f;
        uint4 ua = __builtin_bit_cast(uint4, a);
        uint4 ub = __builtin_bit_cast(uint4, b);
        ub.z = __float_as_uint(dis[node]);
        ub.w = 0u;
        uint4* dst = t1 + (size_t)node * 2;
        dst[0] = ua;
        dst[1] = ub;
    }
}

// Scatter-mode aggregation (R6): one block per 128-node fine bucket.
// The bucket's partB records are contiguous -> DMA-stage in 32KB chunks,
// then each thread gathers h[src] and ds_add_f32's norm*h into acc[c][*].
// No node-sorted csr, no row_ptr, no bucket_csr sort kernel needed at all.
// norm = ew(raw, partB) * dis_src(packed in h row) * dis_dst(sdis[c]).
// Epilogue (thread/node): relu(acc + dis^2*h_own + bias), next-layer matmul.
template <int DIN, int ROWW, int DOUT, bool LAST>
__global__ __launch_bounds__(512, 4)
void agg_kernel(const uint2* __restrict__ partB, const int* __restrict__ fbase,
                const float* __restrict__ dis, const uint4* __restrict__ hin,
                const float* __restrict__ b_this, const float* __restrict__ W_next,
                const float* __restrict__ b_next, void* __restrict__ hout_v, int N) {
    __shared__ uint2 stage[ACHUNK];
    __shared__ float acc[RANGE * DIN];
    __shared__ float sdis[RANGE];
    int b = blockIdx.x, tid = threadIdx.x;
    int s = fbase[b], t = fbase[b + 1];
    int cnt = t - s;
    for (int i = tid; i < RANGE * DIN; i += 512) acc[i] = 0.f;
    if (tid < RANGE) {
        int node = b * RANGE + tid;
        sdis[tid] = (node < N) ? dis[node] : 0.f;
    }

    auto scatter1 = [&](uint2 r) {
        int src = (int)(r.x & 0x1FFFFu);
        int c   = (int)((r.x >> 17) & (RANGE - 1));
        float ew = __uint_as_float(r.y);
        const uint4* hr = hin + (size_t)src * ROWW;
        float* ac = acc + c * DIN;
        if constexpr (DIN == 12) {
            uint4 ua = hr[0], ub = hr[1];
            float norm = ew * __uint_as_float(ub.z) * sdis[c];
            h8 a = __builtin_bit_cast(h8, ua);
            h8 bb = __builtin_bit_cast(h8, ub);
#pragma unroll
            for (int d = 0; d < 8; d++) atomicAdd(&ac[d], norm * (float)a[d]);
#pragma unroll
            for (int d = 0; d < 4; d++) atomicAdd(&ac[8 + d], norm * (float)bb[d]);
        } else if constexpr (DIN == 6) {
            uint4 u = hr[0];
            float norm = ew * __uint_as_float(u.w) * sdis[c];
            h8 a = __builtin_bit_cast(h8, u);
#pragma unroll
            for (int d = 0; d < 6; d++) atomicAdd(&ac[d], norm * (float)a[d]);
        } else {
            uint4 u = hr[0];
            float norm = ew * __uint_as_float(u.z) * sdis[c];
            h8 a = __builtin_bit_cast(h8, u);
#pragma unroll
            for (int d = 0; d < 3; d++) atomicAdd(&ac[d], norm * (float)a[d]);
        }
    };

    int nch = (cnt + ACHUNK - 1) / ACHUNK;
    for (int ch = 0; ch < nch; ++ch) {
        int cb  = ch * ACHUNK;
        int clim = min(cnt - cb, ACHUNK);
        {   // DMA stage: 8 waves x 64 lanes x 16 B = 1024 recs/iter
            int wave = tid >> 6, lane = tid & 63;
            int iters = (clim + 1023) >> 10;   // rounds up; partB is +1024-rec padded
            for (int it = 0; it < iters; ++it) {
                int rb = (it << 10) + (wave << 7);             // wave-uniform
                const uint2* src = partB + s + cb + rb + (lane << 1);
                GLOAD_LDS16(src, (char*)stage + ((size_t)rb << 3));
            }
        }
        asm volatile("s_waitcnt vmcnt(0)" ::: "memory");
        __syncthreads();   // also covers acc/sdis init on first iteration
        int i = tid;
        for (; i + 512 < clim; i += 1024) {    // dual independent gather chains
            uint2 r0 = stage[i];
            uint2 r1 = stage[i + 512];
            scatter1(r0);
            scatter1(r1);
        }
        if (i < clim) scatter1(stage[i]);
        __syncthreads();   // stage consumed before next chunk's DMA overwrites
    }
    __syncthreads();       // nch==0 path: init visible before epilogue

    if (tid < RANGE) {
        int node = b * RANGE + tid;
        if (node < N) {
            const uint4* hn = hin + (size_t)node * ROWW;
            float dn = sdis[tid];
            float s2 = dn * dn;
            float v[DIN];
            if constexpr (DIN == 12) {
                uint4 ua = hn[0], ub = hn[1];
                h8 a = __builtin_bit_cast(h8, ua);
                h8 bb = __builtin_bit_cast(h8, ub);
#pragma unroll
                for (int d = 0; d < 8; d++)
                    v[d] = fmaxf(acc[tid * DIN + d] + s2 * (float)a[d] + b_this[d], 0.f);
#pragma unroll
                for (int d = 0; d < 4; d++)
                    v[8 + d] = fmaxf(acc[tid * DIN + 8 + d] + s2 * (float)bb[d] + b_this[8 + d], 0.f);
            } else if constexpr (DIN == 6) {
                uint4 u = hn[0];
                h8 a = __builtin_bit_cast(h8, u);
#pragma unroll
                for (int d = 0; d < 6; d++)
                    v[d] = fmaxf(acc[tid * DIN + d] + s2 * (float)a[d] + b_this[d], 0.f);
            } else {
                uint4 u = hn[0];
                h8 a = __builtin_bit_cast(h8, u);
#pragma unroll
                for (int d = 0; d < 3; d++)
                    v[d] = fmaxf(acc[tid * DIN + d] + s2 * (float)a[d] + b_this[d], 0.f);
            }
            if constexpr (!LAST) {
                float o[DOUT];
#pragma unroll
                for (int oo = 0; oo < DOUT; oo++) {
                    float z = 0.f;
#pragma unroll
                    for (int d = 0; d < DIN; d++) z += v[d] * W_next[d * DOUT + oo];
                    o[oo] = z;
                }
                h8 w;
#pragma unroll
                for (int oo = 0; oo < 8; oo++) w[oo] = (_Float16)0.f;
#pragma unroll
                for (int oo = 0; oo < DOUT; oo++) w[oo] = (_Float16)o[oo];
                uint4 uw = __builtin_bit_cast(uint4, w);
                if constexpr (DOUT == 6) uw.w = __float_as_uint(dn);
                else                     uw.z = __float_as_uint(dn);
                ((uint4*)hout_v)[node] = uw;
            } else {
                float z = b_next[0];
#pragma unroll
                for (int d = 0; d < DIN; d++) z += v[d] * W_next[d];
                ((float*)hout_v)[node] = 1.0f / (1.0f + expf(-z));
            }
        }
    }
}

// ---------------------------------------------------------------------------
extern "C" void kernel_launch(void* const* d_in, const int* in_sizes, int n_in,
                              void* d_out, int out_size, void* d_ws, size_t ws_size,
                              hipStream_t stream) {
    const float* X  = (const float*)d_in[0];
    const int*   ei = (const int*)d_in[1];
    const float* ew = (const float*)d_in[2];
    const float* W1 = (const float*)d_in[3];
    const float* b1 = (const float*)d_in[4];
    const float* W2 = (const float*)d_in[5];
    const float* b2 = (const float*)d_in[6];
    const float* W3 = (const float*)d_in[7];
    const float* b3 = (const float*)d_in[8];
    const float* Wl = (const float*)d_in[9];
    const float* bl = (const float*)d_in[10];
    float* out = (float*)d_out;

    const int N = in_sizes[0] / 128;
    const int E = in_sizes[1] / 2;
    const int* row = ei;
    const int* col = ei + E;
    const int nfine   = (N + RANGE - 1) >> RSHIFT;
    const int ncoarse = (N + CRANGE - 1) >> CSHIFT;

    char* ws = (char*)d_ws;
    size_t off = 0;
    auto carve = [&](size_t bytes) -> void* {
        void* p = ws + off;
        off += (bytes + 255) & ~(size_t)255;
        return p;
    };
    int*   fcnt    = (int*)  carve((size_t)MAXBUCK * PAD * 4);
    int*   fcur    = (int*)  carve((size_t)MAXBUCK * PAD * 4);
    int*   ccur    = (int*)  carve((size_t)MAXC * PAD * 4);
    int*   cbase   = (int*)  carve((size_t)(MAXC + 1) * 4);
    int*   fbase   = (int*)  carve((size_t)(MAXBUCK + 1) * 4);
    float* dis     = (float*)carve((size_t)N * 4);
    uint2* partA   = (uint2*)carve((size_t)E * 8);
    uint2* partB   = (uint2*)carve((size_t)(E + 1024) * 8);   // +1024 recs: DMA tail over-read pad
    // R6: partB stays live through all aggs (scatter mode reads it);
    // partA is dead after fine_scatter -> t1/t2/t3 live there now.
    uint4* t1  = (uint4*)partA;                 // N rows x 2 uint4 (32 B)
    uint4* t2  = t1 + (size_t)N * 2;            // N rows x 1 uint4 (16 B)
    uint4* t3  = t2 + (size_t)N;                // N rows x 1 uint4 (16 B)
    (void)ws_size; (void)n_in; (void)out_size;

    const int bCnt = (E + CH_CNT - 1) / CH_CNT;
    const int bSc  = (E + CH_SC - 1) / CH_SC;       // 1563 scatter blocks
    const int bL   = ((size_t)N * 8 + 255) / 256;   // lin1: 8 lanes per node

    zero_pad_kernel<<<(nfine + 255) / 256, 256, 0, stream>>>(fcnt, nfine);
    count_kernel<<<bCnt, 256, 0, stream>>>(col, fcnt, nfine, E);
    scan_kernel<<<1, 1024, 0, stream>>>(fcnt, fbase, fcur, cbase, ccur,
                                        nfine, ncoarse, E);
    coarse_scatter_kernel<<<bSc, 256, 0, stream>>>(row, col, ew, ccur, partA, ncoarse, E);
    fine_scatter_kernel<<<bSc, 256, 0, stream>>>(partA, cbase, fcur, partB, nfine, ncoarse, E);
    deg_kernel<<<nfine, 512, 0, stream>>>(partB, fbase, dis, N);
    lin1_kernel<<<bL, 256, 0, stream>>>(X, W1, dis, t1, N);
    agg_kernel<12, 2, 6, false><<<nfine, 512, 0, stream>>>(partB, fbase, dis, t1, b1, W2, nullptr, t2, N);
    agg_kernel< 6, 1, 3, false><<<nfine, 512, 0, stream>>>(partB, fbase, dis, t2, b2, W3, nullptr, t3, N);
    agg_kernel< 3, 1, 1, true ><<<nfine, 512, 0, stream>>>(partB, fbase, dis, t3, b3, Wl, bl, out, N);
}

// Round 8
// 467.558 us; speedup vs baseline: 2.6502x; 2.6502x over previous
//
#include <hip/hip_runtime.h>
#include <cstdint>
#include <cstddef>

#define RANGE    128       // nodes per fine bucket
#define RSHIFT   7
#define MAXBUCK  800       // >= ceil(N/RANGE); N=100K -> 782
#define CSHIFT   12        // nodes per coarse bucket = 4096
#define CRANGE   4096
#define MAXC     32        // >= ceil(N/CRANGE); N=100K -> 25
#define FPB      32        // fine buckets per coarse bucket
#define CH_CNT   8192      // edges per block, count pass
#define CH_SC    4096      // edges per block, scatter passes
#define EPT      16        // CH_SC / 256
#define PAD      16        // pad global counters to one 64B line each
#define WSTR     132       // LDS stride for transposed W1 (16B-aligned, rotates banks)
#define STAGE_CAP 9216     // bucket_csr LDS stage = 9 x 1024 recs (mean 8192 + 11 sigma)
#define KMAX     18        // ceil(STAGE_CAP / 512) regs held per thread in reg-permute
#define SCAP     3072      // agg csr LDS stage, records (32 nodes * mean 64 = 2048, +22 sigma)

typedef _Float16 h8 __attribute__((ext_vector_type(8)));

// DMA a 16B-per-lane chunk global->LDS. lds byte base must be wave-uniform;
// HW writes lds_base + lane*16; global src is per-lane.
#define GLOAD_LDS16(gsrc, ldsb)                                                   \
    __builtin_amdgcn_global_load_lds(                                             \
        (const __attribute__((address_space(1))) uint32_t*)(gsrc),                \
        (__attribute__((address_space(3))) uint32_t*)(ldsb), 16, 0, 0)

#define WAITV(n) asm volatile("s_waitcnt vmcnt(" #n ")" ::: "memory")

// ---------------------------------------------------------------------------
__global__ void zero_pad_kernel(int* __restrict__ p, int n) {
    int i = blockIdx.x * blockDim.x + threadIdx.x;
    if (i < n) p[i * PAD] = 0;
}

// fine histogram (782 buckets) of col>>7; per-block LDS, merged w/ global atomics
__global__ void count_kernel(const int* __restrict__ col, int* __restrict__ fcnt,
                             int nfine, int E) {
    __shared__ int lcnt[MAXBUCK];
    int tid = threadIdx.x;
    for (int i = tid; i < nfine; i += blockDim.x) lcnt[i] = 0;
    __syncthreads();
    int base = blockIdx.x * CH_CNT;
    int end  = min(E, base + CH_CNT);
    for (int e = base + tid; e < end; e += blockDim.x)
        atomicAdd(&lcnt[col[e] >> RSHIFT], 1);
    __syncthreads();
    for (int i = tid; i < nfine; i += blockDim.x)
        if (lcnt[i]) atomicAdd(&fcnt[i * PAD], lcnt[i]);
}

// scan fine counts -> fine bases/cursors; derive coarse bases/cursors
__global__ void scan_kernel(const int* __restrict__ fcnt, int* __restrict__ fbase,
                            int* __restrict__ fcur, int* __restrict__ cbase,
                            int* __restrict__ ccur, int* __restrict__ row_ptr,
                            int nfine, int ncoarse, int N, int E) {
    __shared__ int lds[1024];
    int T = threadIdx.x;
    int s = (T < nfine) ? fcnt[T * PAD] : 0;
    lds[T] = s;
    __syncthreads();
    for (int off = 1; off < 1024; off <<= 1) {
        int v = (T >= off) ? lds[T - off] : 0;
        __syncthreads();
        lds[T] += v;
        __syncthreads();
    }
    int excl = lds[T] - s;
    if (T < nfine) { fbase[T] = excl; fcur[T * PAD] = excl; }
    if ((T & (FPB - 1)) == 0 && (T >> 5) < ncoarse) {
        cbase[T >> 5] = excl;
        ccur[(T >> 5) * PAD] = excl;
    }
    if (T == 0) { fbase[nfine] = E; cbase[ncoarse] = E; row_ptr[N] = E; }
}

// coarse scatter with LDS counting-sort staging: records leave the block
// bucket-sorted, so global stores are fully coalesced dense segments.
// record = {row | col_low12<<17, ew}
__global__ void coarse_scatter_kernel(const int* __restrict__ row, const int* __restrict__ col,
                                      const float* __restrict__ ew, int* __restrict__ ccur,
                                      uint2* __restrict__ partA, int ncoarse, int E) {
    __shared__ uint2 stage[CH_SC];
    __shared__ unsigned char sb[CH_SC];
    __shared__ int lcnt[MAXC], lofs[MAXC], gofs[MAXC];
    __shared__ int total_s;
    int tid = threadIdx.x;
    if (tid < MAXC) lcnt[tid] = 0;
    __syncthreads();
    int base = blockIdx.x * CH_SC;
    int cnt  = min(E - base, CH_SC);

    uint2 rec[EPT]; int rnk[EPT]; int bb[EPT];
#pragma unroll
    for (int k = 0; k < EPT; k++) {
        int idx = tid + (k << 8);
        if (idx < cnt) {
            int e = base + idx;
            int c = col[e];
            int b = c >> CSHIFT;
            bb[k]  = b;
            rec[k] = make_uint2((unsigned)row[e] | ((unsigned)(c & (CRANGE - 1)) << 17),
                                __float_as_uint(ew[e]));
            rnk[k] = atomicAdd(&lcnt[b], 1);   // one LDS atomic per edge; rank kept in regs
        }
    }
    __syncthreads();
    if (tid == 0) {  // 25-entry serial scan
        int run = 0;
        for (int i = 0; i < ncoarse; i++) { lofs[i] = run; run += lcnt[i]; }
        total_s = run;
    }
    __syncthreads();
    if (tid < ncoarse) {
        int c = lcnt[tid];
        if (c) {
            int g = atomicAdd(&ccur[tid * PAD], c);
            gofs[tid] = g - lofs[tid];
        }
    }
#pragma unroll
    for (int k = 0; k < EPT; k++) {
        int idx = tid + (k << 8);
        if (idx < cnt) {
            int p = lofs[bb[k]] + rnk[k];
            stage[p] = rec[k];
            sb[p] = (unsigned char)bb[k];
        }
    }
    __syncthreads();
    int total = total_s;
    for (int i = tid; i < total; i += 256)   // dense, coalesced copy-out
        partA[gofs[sb[i]] + i] = stage[i];
}

// fine scatter (same staging scheme): partA (coarsely sorted) -> partB grouped
// by 128-node fine bucket.  output record = {row | dst_local<<17, ew}
__global__ __launch_bounds__(256, 3)
void fine_scatter_kernel(const uint2* __restrict__ partA, const int* __restrict__ cbase,
                                    int* __restrict__ fcur, uint2* __restrict__ partB,
                                    int nfine, int ncoarse, int E) {
    __shared__ uint2 stage[CH_SC];
    __shared__ unsigned short sb[CH_SC];
    __shared__ int lcnt[MAXBUCK], lofs[MAXBUCK], gofs[MAXBUCK];
    __shared__ int tmp[256];
    __shared__ int scb[MAXC + 1];
    __shared__ int rlo_s, total_s;
    int tid = threadIdx.x;
    int base = blockIdx.x * CH_SC;
    int cnt  = min(E - base, CH_SC);
    if (tid <= ncoarse) scb[tid] = cbase[tid];
    for (int i = tid; i < nfine; i += 256) lcnt[i] = 0;
    if (tid == 0) {
        int r = 0;
        while (r < ncoarse - 1 && cbase[r + 1] <= base) ++r;
        rlo_s = r;
    }
    __syncthreads();
    int rlo = rlo_s;

    uint2 rec[EPT]; int rnk[EPT]; int ff[EPT];
#pragma unroll
    for (int k = 0; k < EPT; k++) {
        int idx = tid + (k << 8);
        if (idx < cnt) {
            int e = base + idx;
            uint2 v = partA[e];
            int r = rlo;
            while (e >= scb[r + 1]) ++r;   // short walk: chunk spans ~2 regions
            int col12 = (int)((v.x >> 17) & (CRANGE - 1));
            int f = (r << 5) | (col12 >> RSHIFT);
            ff[k]  = f;
            rec[k] = make_uint2((v.x & 0x1FFFFu) | ((unsigned)(col12 & (RANGE - 1)) << 17), v.y);
            rnk[k] = atomicAdd(&lcnt[f], 1);
        }
    }
    __syncthreads();
    {   // parallel exclusive scan of lcnt[0..nfine) -> lofs
        const int Cc = (nfine + 255) >> 8;   // 4 counters per thread
        int b0 = tid * Cc;
        int s = 0;
        for (int i = 0; i < Cc; i++) {
            int idx = b0 + i;
            if (idx < nfine) s += lcnt[idx];
        }
        tmp[tid] = s;
        __syncthreads();
        for (int off = 1; off < 256; off <<= 1) {
            int v = (tid >= off) ? tmp[tid - off] : 0;
            __syncthreads();
            tmp[tid] += v;
            __syncthreads();
        }
        int run = tmp[tid] - s;
        for (int i = 0; i < Cc; i++) {
            int idx = b0 + i;
            if (idx < nfine) { lofs[idx] = run; run += lcnt[idx]; }
        }
        if (tid == 255) total_s = tmp[255];
    }
    __syncthreads();
    for (int i = tid; i < nfine; i += 256) {
        int c = lcnt[i];
        if (c) {
            int g = atomicAdd(&fcur[i * PAD], c);
            gofs[i] = g - lofs[i];
        }
    }
#pragma unroll
    for (int k = 0; k < EPT; k++) {
        int idx = tid + (k << 8);
        if (idx < cnt) {
            int p = lofs[ff[k]] + rnk[k];
            stage[p] = rec[k];
            sb[p] = (unsigned short)ff[k];
        }
    }
    __syncthreads();
    int total = total_s;
    for (int i = tid; i < total; i += 256)   // dense, coalesced copy-out
        partB[gofs[sb[i]] + i] = stage[i];
}

// one block per fine bucket: per-node CSR + row_ptr + dis, all in LDS.
// v5 (R7): R7's scatter-agg experiment failed (LDS-atomic serialization,
// 514us) -> reverted to the R6 pull-mode pipeline. This round's contained
// change: pipelined count under DMA (T4 counted-vmcnt). Each wave issues all
// 9 chunk-DMAs (9*1024 = STAGE_CAP recs, unconditional; partB padded), then
// counts ITS OWN 128-rec slice after each s_waitcnt vmcnt(8..0) — the count
// phase overlaps the DMA instead of serializing behind a vmcnt(0) drain.
__global__ __launch_bounds__(512, 4)
void bucket_csr_kernel(const uint2* __restrict__ part, const int* __restrict__ bbase,
                       int* __restrict__ row_ptr, float* __restrict__ dis,
                       uint2* __restrict__ csr, int N) {
    extern __shared__ uint2 stage[];          // STAGE_CAP records (dynamic LDS)
    __shared__ int   scnt[RANGE];
    __shared__ int   sscan[RANGE];
    __shared__ float sdeg[RANGE];
    __shared__ float sdis[RANGE];
    int b = blockIdx.x, tid = threadIdx.x;
    int s = bbase[b], t = bbase[b + 1];
    int cnt = t - s;
    int lim = min(cnt, STAGE_CAP);
    if (tid < RANGE) { scnt[tid] = 0; sdeg[tid] = 1.0f; }  // self-loop weight
    __syncthreads();   // init visible before pipelined counting begins
    int wave = tid >> 6, lane = tid & 63;
    // issue all 9 chunk-DMAs (wave-uniform LDS base, per-lane global src)
#pragma unroll
    for (int it = 0; it < 9; ++it) {
        int recBase = (it << 10) + (wave << 7);
        const uint2* src = part + s + recBase + (lane << 1);
        GLOAD_LDS16(src, (char*)stage + ((size_t)recBase << 3));
    }
    // pipelined count: after own it-th load retires, count own 128-rec slice
    auto cslice = [&](int it) {
        int i0 = (it << 10) + (wave << 7) + lane;
#pragma unroll
        for (int q = 0; q < 2; ++q) {
            int idx = i0 + (q << 6);
            if (idx < lim) {
                uint2 r = stage[idx];
                int c = (r.x >> 17) & (RANGE - 1);
                atomicAdd(&scnt[c], 1);
                atomicAdd(&sdeg[c], __uint_as_float(r.y));
            }
        }
    };
    WAITV(8); cslice(0);
    WAITV(7); cslice(1);
    WAITV(6); cslice(2);
    WAITV(5); cslice(3);
    WAITV(4); cslice(4);
    WAITV(3); cslice(5);
    WAITV(2); cslice(6);
    WAITV(1); cslice(7);
    WAITV(0); cslice(8);
    // tail beyond STAGE_CAP (never for this distribution)
    for (int idx = STAGE_CAP + tid; idx < cnt; idx += 512) {
        uint2 r = part[s + idx];
        int c = (r.x >> 17) & (RANGE - 1);
        atomicAdd(&scnt[c], 1);
        atomicAdd(&sdeg[c], __uint_as_float(r.y));
    }
    __syncthreads();
    int cnt_t = 0;
    if (tid < RANGE) { cnt_t = scnt[tid]; sscan[tid] = cnt_t; }
    __syncthreads();
    for (int off = 1; off < RANGE; off <<= 1) {
        int v = 0;
        if (tid < RANGE && tid >= off) v = sscan[tid - off];
        __syncthreads();
        if (tid < RANGE) sscan[tid] += v;
        __syncthreads();
    }
    if (tid < RANGE) {
        int excl = sscan[tid] - cnt_t;
        int node = b * RANGE + tid;
        float dn = rsqrtf(sdeg[tid]);
        sdis[tid] = dn;
        if (node < N) {
            row_ptr[node] = s + excl;
            dis[node] = dn;
        }
        scnt[tid] = excl;  // reuse as within-bucket cursor
    }
    __syncthreads();

    if (cnt <= STAGE_CAP) {
        // fast path: reg-held permute, single global read total
        uint2 rc[KMAX]; int rp[KMAX];
#pragma unroll
        for (int k = 0; k < KMAX; k++) {
            int idx = tid + k * 512;
            if (idx < cnt) {
                uint2 r = stage[idx];
                int c   = (r.x >> 17) & (RANGE - 1);
                float v = sdis[c] * __uint_as_float(r.y);   // ew * dis_dst
                rp[k] = atomicAdd(&scnt[c], 1);
                rc[k] = make_uint2(r.x & 0x1FFFFu, __float_as_uint(v));
            }
        }
        __syncthreads();   // all reads done before in-place overwrite
#pragma unroll
        for (int k = 0; k < KMAX; k++) {
            int idx = tid + k * 512;
            if (idx < cnt) stage[rp[k]] = rc[k];
        }
        __syncthreads();
        for (int i = tid; i < cnt; i += 512)   // dense, coalesced copy-out
            csr[s + i] = stage[i];
    } else {
        // overflow fallback (never for this distribution): scattered stores
        for (int idx = tid; idx < cnt; idx += 512) {
            uint2 r = (idx < STAGE_CAP) ? stage[idx] : part[s + idx];
            int c   = (r.x >> 17) & (RANGE - 1);
            float v = sdis[c] * __uint_as_float(r.y);
            int off = atomicAdd(&scnt[c], 1);
            csr[s + off] = make_uint2(r.x & 0x1FFFFu, __float_as_uint(v));
        }
    }
}

// t1 = fp16(X @ W1) + packed dis.  8 lanes per node: each lane owns 16 of the
// 128 inputs (4 coalesced float4 loads), W1 transposed in LDS (stride 132),
// 192 independent FMAs per lane, then 3-step shuffle reduction.
__global__ void lin1_kernel(const float* __restrict__ X, const float* __restrict__ W1,
                            const float* __restrict__ dis, uint4* __restrict__ t1, int n) {
    __shared__ float w1t[12 * WSTR];
    int tid = threadIdx.x;
    for (int i = tid; i < 128 * 12; i += 256) {
        int k = i / 12, o = i - k * 12;
        w1t[o * WSTR + k] = W1[i];
    }
    __syncthreads();
    int gt   = blockIdx.x * 256 + tid;
    int node = gt >> 3;
    int sub  = gt & 7;
    if (node >= n) return;

    const float4* xp = (const float4*)(X + (size_t)node * 128 + sub * 16);
    float4 x0 = xp[0], x1 = xp[1], x2 = xp[2], x3 = xp[3];

    float res[12];
#pragma unroll
    for (int o = 0; o < 12; o++) {
        const float4* wp = (const float4*)(w1t + o * WSTR + sub * 16);
        float4 w0 = wp[0], w1v = wp[1], w2 = wp[2], w3 = wp[3];
        float s;
        s  = x0.x * w0.x + x0.y * w0.y + x0.z * w0.z + x0.w * w0.w;
        s += x1.x * w1v.x + x1.y * w1v.y + x1.z * w1v.z + x1.w * w1v.w;
        s += x2.x * w2.x + x2.y * w2.y + x2.z * w2.z + x2.w * w2.w;
        s += x3.x * w3.x + x3.y * w3.y + x3.z * w3.z + x3.w * w3.w;
        res[o] = s;
    }
#pragma unroll
    for (int o = 0; o < 12; o++) {
        res[o] += __shfl_xor(res[o], 1, 64);
        res[o] += __shfl_xor(res[o], 2, 64);
        res[o] += __shfl_xor(res[o], 4, 64);
    }
    if (sub == 0) {
        h8 a, b;
#pragma unroll
        for (int o = 0; o < 8; o++) a[o] = (_Float16)res[o];
#pragma unroll
        for (int o = 0; o < 4; o++) b[o] = (_Float16)res[8 + o];
#pragma unroll
        for (int o = 4; o < 8; o++) b[o] = (_Float16)0.f;
        uint4 ua = __builtin_bit_cast(uint4, a);
        uint4 ub = __builtin_bit_cast(uint4, b);
        ub.z = __float_as_uint(dis[node]);
        ub.w = 0u;
        uint4* dst = t1 + (size_t)node * 2;
        dst[0] = ua;
        dst[1] = ub;
    }
}

// Pull aggregation, 8 lanes per node, 32 nodes per 256-thr block.
// (verified R6 form): block's contiguous csr segment is DMA-staged into LDS;
// inner loop reads records from LDS, only the feature gather stays on VMEM
// (dual chains in flight).
template <int DIN, int ROWW, int DOUT, bool LAST>
__global__ __launch_bounds__(256)
void agg_kernel(const int* __restrict__ row_ptr, const uint2* __restrict__ csr,
                const uint4* __restrict__ hin,
                const float* __restrict__ b_this, const float* __restrict__ W_next,
                const float* __restrict__ b_next, void* __restrict__ hout_v, int n) {
    __shared__ uint2 scsr[SCAP];
    int tid = threadIdx.x;
    int nodeBase = blockIdx.x << 5;          // 32 nodes per block
    int node = nodeBase + (tid >> 3);
    int sub  = tid & 7;
    int endNode  = min(nodeBase + 32, n);
    int blkStart = row_ptr[nodeBase];
    int blkEnd   = row_ptr[endNode];
    int blkCnt   = blkEnd - blkStart;
    int lim = min(blkCnt, SCAP);
    {   // DMA stage: 4 waves x 64 lanes x 16 B = 512 recs/iter
        int wave = tid >> 6, lane = tid & 63;
        int iters = (lim + 511) >> 9;        // rounds up; over-read inside ws pad
        for (int it = 0; it < iters; ++it) {
            int recBase = (it << 9) + (wave << 7);         // wave-uniform
            const uint2* src = csr + blkStart + recBase + (lane << 1);
            GLOAD_LDS16(src, (char*)scsr + ((size_t)recBase << 3));
        }
    }
    asm volatile("s_waitcnt vmcnt(0)" ::: "memory");
    __syncthreads();

    if (node >= n) return;                   // after barrier: safe
    int start = row_ptr[node];
    int end   = row_ptr[node + 1];
    float acc[DIN], acc2[DIN];
#pragma unroll
    for (int d = 0; d < DIN; d++) { acc[d] = 0.f; acc2[d] = 0.f; }

    auto body = [&](uint2 r, float* a_) {
        int src    = (int)(r.x);
        float ewdd = __uint_as_float(r.y);
        const uint4* hr = hin + (size_t)src * ROWW;
        if constexpr (DIN == 12) {
            uint4 ua = hr[0], ub = hr[1];
            float norm = ewdd * __uint_as_float(ub.z);
            h8 a = __builtin_bit_cast(h8, ua);
            h8 b = __builtin_bit_cast(h8, ub);
#pragma unroll
            for (int d = 0; d < 8; d++) a_[d] += norm * (float)a[d];
#pragma unroll
            for (int d = 0; d < 4; d++) a_[8 + d] += norm * (float)b[d];
        } else if constexpr (DIN == 6) {
            uint4 u = hr[0];
            float norm = ewdd * __uint_as_float(u.w);
            h8 a = __builtin_bit_cast(h8, u);
#pragma unroll
            for (int d = 0; d < 6; d++) a_[d] += norm * (float)a[d];
        } else {  // DIN == 3
            uint4 u = hr[0];
            float norm = ewdd * __uint_as_float(u.z);
            h8 a = __builtin_bit_cast(h8, u);
#pragma unroll
            for (int d = 0; d < 3; d++) a_[d] += norm * (float)a[d];
        }
    };

    if (blkCnt <= SCAP) {                    // block-uniform fast path
        int ls = start - blkStart;
        int le = end - blkStart;
        int e = ls + sub;
        for (; e + 8 < le; e += 16) {        // dual independent gather chains
            uint2 r0 = scsr[e];
            uint2 r1 = scsr[e + 8];
            body(r0, acc);
            body(r1, acc2);
        }
        if (e < le) body(scsr[e], acc);
    } else {                                 // overflow fallback: global reads
        int e = start + sub;
        for (; e + 8 < end; e += 16) {
            uint2 r0 = csr[e];
            uint2 r1 = csr[e + 8];
            body(r0, acc);
            body(r1, acc2);
        }
        if (e < end) body(csr[e], acc);
    }

#pragma unroll
    for (int d = 0; d < DIN; d++) {
        acc[d] += acc2[d];
        acc[d] += __shfl_xor(acc[d], 1, 64);
        acc[d] += __shfl_xor(acc[d], 2, 64);
        acc[d] += __shfl_xor(acc[d], 4, 64);
    }

    if (sub == 0) {
        const uint4* hn = hin + (size_t)node * ROWW;
        float v[DIN];
        float dn;
        if constexpr (DIN == 12) {
            uint4 ua = hn[0], ub = hn[1];
            dn = __uint_as_float(ub.z);
            float s2 = dn * dn;
            h8 a = __builtin_bit_cast(h8, ua);
            h8 b = __builtin_bit_cast(h8, ub);
#pragma unroll
            for (int d = 0; d < 8; d++) v[d] = fmaxf(acc[d] + s2 * (float)a[d] + b_this[d], 0.f);
#pragma unroll
            for (int d = 0; d < 4; d++) v[8 + d] = fmaxf(acc[8 + d] + s2 * (float)b[d] + b_this[8 + d], 0.f);
        } else if constexpr (DIN == 6) {
            uint4 u = hn[0];
            dn = __uint_as_float(u.w);
            float s2 = dn * dn;
            h8 a = __builtin_bit_cast(h8, u);
#pragma unroll
            for (int d = 0; d < 6; d++) v[d] = fmaxf(acc[d] + s2 * (float)a[d] + b_this[d], 0.f);
        } else {
            uint4 u = hn[0];
            dn = __uint_as_float(u.z);
            float s2 = dn * dn;
            h8 a = __builtin_bit_cast(h8, u);
#pragma unroll
            for (int d = 0; d < 3; d++) v[d] = fmaxf(acc[d] + s2 * (float)a[d] + b_this[d], 0.f);
        }
        if constexpr (!LAST) {
            float o[DOUT];
#pragma unroll
            for (int oo = 0; oo < DOUT; oo++) {
                float z = 0.f;
#pragma unroll
                for (int d = 0; d < DIN; d++) z += v[d] * W_next[d * DOUT + oo];
                o[oo] = z;
            }
            h8 w;
#pragma unroll
            for (int oo = 0; oo < 8; oo++) w[oo] = (_Float16)0.f;
#pragma unroll
            for (int oo = 0; oo < DOUT; oo++) w[oo] = (_Float16)o[oo];
            uint4 uw = __builtin_bit_cast(uint4, w);
            if constexpr (DOUT == 6) uw.w = __float_as_uint(dn);
            else                     uw.z = __float_as_uint(dn);
            ((uint4*)hout_v)[node] = uw;
        } else {
            float z = b_next[0];
#pragma unroll
            for (int d = 0; d < DIN; d++) z += v[d] * W_next[d];
            ((float*)hout_v)[node] = 1.0f / (1.0f + expf(-z));
        }
    }
}

// ---------------------------------------------------------------------------
extern "C" void kernel_launch(void* const* d_in, const int* in_sizes, int n_in,
                              void* d_out, int out_size, void* d_ws, size_t ws_size,
                              hipStream_t stream) {
    const float* X  = (const float*)d_in[0];
    const int*   ei = (const int*)d_in[1];
    const float* ew = (const float*)d_in[2];
    const float* W1 = (const float*)d_in[3];
    const float* b1 = (const float*)d_in[4];
    const float* W2 = (const float*)d_in[5];
    const float* b2 = (const float*)d_in[6];
    const float* W3 = (const float*)d_in[7];
    const float* b3 = (const float*)d_in[8];
    const float* Wl = (const float*)d_in[9];
    const float* bl = (const float*)d_in[10];
    float* out = (float*)d_out;

    const int N = in_sizes[0] / 128;
    const int E = in_sizes[1] / 2;
    const int* row = ei;
    const int* col = ei + E;
    const int nfine   = (N + RANGE - 1) >> RSHIFT;
    const int ncoarse = (N + CRANGE - 1) >> CSHIFT;

    char* ws = (char*)d_ws;
    size_t off = 0;
    auto carve = [&](size_t bytes) -> void* {
        void* p = ws + off;
        off += (bytes + 255) & ~(size_t)255;
        return p;
    };
    int*   fcnt    = (int*)  carve((size_t)MAXBUCK * PAD * 4);
    int*   fcur    = (int*)  carve((size_t)MAXBUCK * PAD * 4);
    int*   ccur    = (int*)  carve((size_t)MAXC * PAD * 4);
    int*   cbase   = (int*)  carve((size_t)(MAXC + 1) * 4);
    int*   fbase   = (int*)  carve((size_t)(MAXBUCK + 1) * 4);
    int*   row_ptr = (int*)  carve((size_t)(N + 1) * 4);
    float* dis     = (float*)carve((size_t)N * 4);
    uint2* partA   = (uint2*)carve((size_t)E * 8);
    uint2* partB   = (uint2*)carve((size_t)(E + STAGE_CAP) * 8);  // pad: always-9-chunk DMA tail over-read
    // csr reuses partA (dead after fine scatter); t1/t2/t3 reuse partB
    uint2* csr = partA;
    uint4* t1  = (uint4*)partB;                 // N rows x 2 uint4 (32 B)
    uint4* t2  = t1 + (size_t)N * 2;            // N rows x 1 uint4 (16 B)
    uint4* t3  = t2 + (size_t)N;                // N rows x 1 uint4 (16 B)
    (void)ws_size; (void)n_in; (void)out_size;

    const int bCnt = (E + CH_CNT - 1) / CH_CNT;
    const int bSc  = (E + CH_SC - 1) / CH_SC;       // 1563 scatter blocks
    const int bL   = ((size_t)N * 8 + 255) / 256;   // lin1: 8 lanes per node
    const int bA   = (N + 31) / 32;                 // agg: 32 nodes per block

    zero_pad_kernel<<<(nfine + 255) / 256, 256, 0, stream>>>(fcnt, nfine);
    count_kernel<<<bCnt, 256, 0, stream>>>(col, fcnt, nfine, E);
    scan_kernel<<<1, 1024, 0, stream>>>(fcnt, fbase, fcur, cbase, ccur, row_ptr,
                                        nfine, ncoarse, N, E);
    coarse_scatter_kernel<<<bSc, 256, 0, stream>>>(row, col, ew, ccur, partA, ncoarse, E);
    fine_scatter_kernel<<<bSc, 256, 0, stream>>>(partA, cbase, fcur, partB, nfine, ncoarse, E);
    bucket_csr_kernel<<<nfine, 512, (size_t)STAGE_CAP * sizeof(uint2), stream>>>(
        partB, fbase, row_ptr, dis, csr, N);
    lin1_kernel<<<bL, 256, 0, stream>>>(X, W1, dis, t1, N);
    agg_kernel<12, 2, 6, false><<<bA, 256, 0, stream>>>(row_ptr, csr, t1, b1, W2, nullptr, t2, N);
    agg_kernel< 6, 1, 3, false><<<bA, 256, 0, stream>>>(row_ptr, csr, t2, b2, W3, nullptr, t3, N);
    agg_kernel< 3, 1, 1, true ><<<bA, 256, 0, stream>>>(row_ptr, csr, t3, b3, Wl, bl, out, N);
}

// Round 9
// 452.922 us; speedup vs baseline: 2.7358x; 1.0323x over previous
//
#include <hip/hip_runtime.h>
#include <cstdint>
#include <cstddef>

#define RANGE    128       // nodes per fine bucket
#define RSHIFT   7
#define MAXBUCK  800       // >= ceil(N/RANGE); N=100K -> 782
#define CSHIFT   12        // nodes per coarse bucket = 4096
#define CRANGE   4096
#define MAXC     32        // >= ceil(N/CRANGE); N=100K -> 25
#define FPB      32        // fine buckets per coarse bucket
#define CH_CNT   8192      // edges per block, count pass
#define CH_SC    4096      // edges per block, scatter passes
#define EPT      16        // CH_SC / 256
#define PAD      16        // pad global counters to one 64B line each
#define WSTR     132       // LDS stride for transposed W1 (16B-aligned, rotates banks)
#define STAGE_CAP 9216     // bucket_csr 4B-rec stage (mean 8192 + 11 sigma) = 36 KB
#define SCAP     3072      // agg csr LDS stage, 4B records = 12 KB

typedef _Float16 h8 __attribute__((ext_vector_type(8)));

// DMA a 16B-per-lane chunk global->LDS. lds byte base must be wave-uniform;
// HW writes lds_base + lane*16; global src is per-lane.
#define GLOAD_LDS16(gsrc, ldsb)                                                   \
    __builtin_amdgcn_global_load_lds(                                             \
        (const __attribute__((address_space(1))) uint32_t*)(gsrc),                \
        (__attribute__((address_space(3))) uint32_t*)(ldsb), 16, 0, 0)

// csr record codec: {src:17 | fp16bits(w):15}, w = ew*dis_dst >= 0 (sign bit 0)
static __device__ __forceinline__ unsigned pack_rec(int src, float w) {
    unsigned short hb = __builtin_bit_cast(unsigned short, (_Float16)w);
    return (unsigned)src | ((unsigned)hb << 17);
}
static __device__ __forceinline__ float rec_w(unsigned rec) {
    unsigned short hb = (unsigned short)(rec >> 17);
    return (float)__builtin_bit_cast(_Float16, hb);
}

// ---------------------------------------------------------------------------
__global__ void zero_pad_kernel(int* __restrict__ p, int n) {
    int i = blockIdx.x * blockDim.x + threadIdx.x;
    if (i < n) p[i * PAD] = 0;
}

// fine histogram (782 buckets) of col>>7; per-block LDS, merged w/ global atomics
__global__ void count_kernel(const int* __restrict__ col, int* __restrict__ fcnt,
                             int nfine, int E) {
    __shared__ int lcnt[MAXBUCK];
    int tid = threadIdx.x;
    for (int i = tid; i < nfine; i += blockDim.x) lcnt[i] = 0;
    __syncthreads();
    int base = blockIdx.x * CH_CNT;
    int end  = min(E, base + CH_CNT);
    for (int e = base + tid; e < end; e += blockDim.x)
        atomicAdd(&lcnt[col[e] >> RSHIFT], 1);
    __syncthreads();
    for (int i = tid; i < nfine; i += blockDim.x)
        if (lcnt[i]) atomicAdd(&fcnt[i * PAD], lcnt[i]);
}

// scan fine counts -> fine bases/cursors; derive coarse bases/cursors
__global__ void scan_kernel(const int* __restrict__ fcnt, int* __restrict__ fbase,
                            int* __restrict__ fcur, int* __restrict__ cbase,
                            int* __restrict__ ccur, int* __restrict__ row_ptr,
                            int nfine, int ncoarse, int N, int E) {
    __shared__ int lds[1024];
    int T = threadIdx.x;
    int s = (T < nfine) ? fcnt[T * PAD] : 0;
    lds[T] = s;
    __syncthreads();
    for (int off = 1; off < 1024; off <<= 1) {
        int v = (T >= off) ? lds[T - off] : 0;
        __syncthreads();
        lds[T] += v;
        __syncthreads();
    }
    int excl = lds[T] - s;
    if (T < nfine) { fbase[T] = excl; fcur[T * PAD] = excl; }
    if ((T & (FPB - 1)) == 0 && (T >> 5) < ncoarse) {
        cbase[T >> 5] = excl;
        ccur[(T >> 5) * PAD] = excl;
    }
    if (T == 0) { fbase[nfine] = E; cbase[ncoarse] = E; row_ptr[N] = E; }
}

// coarse scatter with LDS counting-sort staging: records leave the block
// bucket-sorted, so global stores are fully coalesced dense segments.
// record = {row | col_low12<<17, ew}
__global__ void coarse_scatter_kernel(const int* __restrict__ row, const int* __restrict__ col,
                                      const float* __restrict__ ew, int* __restrict__ ccur,
                                      uint2* __restrict__ partA, int ncoarse, int E) {
    __shared__ uint2 stage[CH_SC];
    __shared__ unsigned char sb[CH_SC];
    __shared__ int lcnt[MAXC], lofs[MAXC], gofs[MAXC];
    __shared__ int total_s;
    int tid = threadIdx.x;
    if (tid < MAXC) lcnt[tid] = 0;
    __syncthreads();
    int base = blockIdx.x * CH_SC;
    int cnt  = min(E - base, CH_SC);

    uint2 rec[EPT]; int rnk[EPT]; int bb[EPT];
#pragma unroll
    for (int k = 0; k < EPT; k++) {
        int idx = tid + (k << 8);
        if (idx < cnt) {
            int e = base + idx;
            int c = col[e];
            int b = c >> CSHIFT;
            bb[k]  = b;
            rec[k] = make_uint2((unsigned)row[e] | ((unsigned)(c & (CRANGE - 1)) << 17),
                                __float_as_uint(ew[e]));
            rnk[k] = atomicAdd(&lcnt[b], 1);   // one LDS atomic per edge; rank kept in regs
        }
    }
    __syncthreads();
    if (tid == 0) {  // 25-entry serial scan
        int run = 0;
        for (int i = 0; i < ncoarse; i++) { lofs[i] = run; run += lcnt[i]; }
        total_s = run;
    }
    __syncthreads();
    if (tid < ncoarse) {
        int c = lcnt[tid];
        if (c) {
            int g = atomicAdd(&ccur[tid * PAD], c);
            gofs[tid] = g - lofs[tid];
        }
    }
#pragma unroll
    for (int k = 0; k < EPT; k++) {
        int idx = tid + (k << 8);
        if (idx < cnt) {
            int p = lofs[bb[k]] + rnk[k];
            stage[p] = rec[k];
            sb[p] = (unsigned char)bb[k];
        }
    }
    __syncthreads();
    int total = total_s;
    for (int i = tid; i < total; i += 256)   // dense, coalesced copy-out
        partA[gofs[sb[i]] + i] = stage[i];
}

// fine scatter (same staging scheme): partA (coarsely sorted) -> partB grouped
// by 128-node fine bucket.  output record = {row | dst_local<<17, ew}
__global__ __launch_bounds__(256, 3)
void fine_scatter_kernel(const uint2* __restrict__ partA, const int* __restrict__ cbase,
                                    int* __restrict__ fcur, uint2* __restrict__ partB,
                                    int nfine, int ncoarse, int E) {
    __shared__ uint2 stage[CH_SC];
    __shared__ unsigned short sb[CH_SC];
    __shared__ int lcnt[MAXBUCK], lofs[MAXBUCK], gofs[MAXBUCK];
    __shared__ int tmp[256];
    __shared__ int scb[MAXC + 1];
    __shared__ int rlo_s, total_s;
    int tid = threadIdx.x;
    int base = blockIdx.x * CH_SC;
    int cnt  = min(E - base, CH_SC);
    if (tid <= ncoarse) scb[tid] = cbase[tid];
    for (int i = tid; i < nfine; i += 256) lcnt[i] = 0;
    if (tid == 0) {
        int r = 0;
        while (r < ncoarse - 1 && cbase[r + 1] <= base) ++r;
        rlo_s = r;
    }
    __syncthreads();
    int rlo = rlo_s;

    uint2 rec[EPT]; int rnk[EPT]; int ff[EPT];
#pragma unroll
    for (int k = 0; k < EPT; k++) {
        int idx = tid + (k << 8);
        if (idx < cnt) {
            int e = base + idx;
            uint2 v = partA[e];
            int r = rlo;
            while (e >= scb[r + 1]) ++r;   // short walk: chunk spans ~2 regions
            int col12 = (int)((v.x >> 17) & (CRANGE - 1));
            int f = (r << 5) | (col12 >> RSHIFT);
            ff[k]  = f;
            rec[k] = make_uint2((v.x & 0x1FFFFu) | ((unsigned)(col12 & (RANGE - 1)) << 17), v.y);
            rnk[k] = atomicAdd(&lcnt[f], 1);
        }
    }
    __syncthreads();
    {   // parallel exclusive scan of lcnt[0..nfine) -> lofs
        const int Cc = (nfine + 255) >> 8;   // 4 counters per thread
        int b0 = tid * Cc;
        int s = 0;
        for (int i = 0; i < Cc; i++) {
            int idx = b0 + i;
            if (idx < nfine) s += lcnt[idx];
        }
        tmp[tid] = s;
        __syncthreads();
        for (int off = 1; off < 256; off <<= 1) {
            int v = (tid >= off) ? tmp[tid - off] : 0;
            __syncthreads();
            tmp[tid] += v;
            __syncthreads();
        }
        int run = tmp[tid] - s;
        for (int i = 0; i < Cc; i++) {
            int idx = b0 + i;
            if (idx < nfine) { lofs[idx] = run; run += lcnt[idx]; }
        }
        if (tid == 255) total_s = tmp[255];
    }
    __syncthreads();
    for (int i = tid; i < nfine; i += 256) {
        int c = lcnt[i];
        if (c) {
            int g = atomicAdd(&fcur[i * PAD], c);
            gofs[i] = g - lofs[i];
        }
    }
#pragma unroll
    for (int k = 0; k < EPT; k++) {
        int idx = tid + (k << 8);
        if (idx < cnt) {
            int p = lofs[ff[k]] + rnk[k];
            stage[p] = rec[k];
            sb[p] = (unsigned short)ff[k];
        }
    }
    __syncthreads();
    int total = total_s;
    for (int i = tid; i < total; i += 256)   // dense, coalesced copy-out
        partB[gofs[sb[i]] + i] = stage[i];
}

// one block per fine bucket: per-node CSR + row_ptr + dis, all in LDS.
// v6 (R8): occupancy attack. Previous forms staged RAW 8B records (72KB LDS
// -> 2 blocks/CU) and all phase-schedule experiments were null (61-67us).
// Now: NO raw stage. Pass 1 stream-counts from global (coalesced, L2-warm);
// scan; pass 2 re-reads global, ranks, writes 4B packed records {src:17|
// fp16(w):15} into a 36KB stage; dense 4B copy-out. LDS ~38KB -> 4 blocks/CU,
// launch_bounds(512,8) caps VGPR<=64 so all 32 waves/CU are resident and the
// per-block serial phases overlap across 4 blocks.
__global__ __launch_bounds__(512, 8)
void bucket_csr_kernel(const uint2* __restrict__ part, const int* __restrict__ bbase,
                       int* __restrict__ row_ptr, float* __restrict__ dis,
                       unsigned* __restrict__ csr, int N) {
    __shared__ unsigned cst[STAGE_CAP];      // 4B records, 36 KB
    __shared__ int   scnt[RANGE];
    __shared__ int   sscan[RANGE];
    __shared__ float sdeg[RANGE];
    __shared__ float sdis[RANGE];
    int b = blockIdx.x, tid = threadIdx.x;
    int s = bbase[b], t = bbase[b + 1];
    int cnt = t - s;
    if (tid < RANGE) { scnt[tid] = 0; sdeg[tid] = 1.0f; }  // self-loop weight
    __syncthreads();
    // pass 1: stream-count from global (independent iterations pipeline)
    for (int i = tid; i < cnt; i += 512) {
        uint2 r = part[s + i];
        int c = (r.x >> 17) & (RANGE - 1);
        atomicAdd(&scnt[c], 1);
        atomicAdd(&sdeg[c], __uint_as_float(r.y));
    }
    __syncthreads();
    int cnt_t = 0;
    if (tid < RANGE) { cnt_t = scnt[tid]; sscan[tid] = cnt_t; }
    __syncthreads();
    for (int off = 1; off < RANGE; off <<= 1) {
        int v = 0;
        if (tid < RANGE && tid >= off) v = sscan[tid - off];
        __syncthreads();
        if (tid < RANGE) sscan[tid] += v;
        __syncthreads();
    }
    if (tid < RANGE) {
        int excl = sscan[tid] - cnt_t;
        int node = b * RANGE + tid;
        float dn = rsqrtf(sdeg[tid]);
        sdis[tid] = dn;
        if (node < N) {
            row_ptr[node] = s + excl;
            dis[node] = dn;
        }
        scnt[tid] = excl;  // reuse as within-bucket (local) cursor
    }
    __syncthreads();
    // pass 2: re-read (L2-warm), rank, write packed 4B rec at sorted local pos
    for (int i = tid; i < cnt; i += 512) {
        uint2 r = part[s + i];
        int c   = (r.x >> 17) & (RANGE - 1);
        int src = (int)(r.x & 0x1FFFFu);
        float w = sdis[c] * __uint_as_float(r.y);   // ew * dis_dst
        unsigned rec = pack_rec(src, w);
        int p = atomicAdd(&scnt[c], 1);
        if (p < STAGE_CAP) cst[p] = rec;            // always, for this distribution
        else               csr[s + p] = rec;        // overflow fallback
    }
    __syncthreads();
    int lim = min(cnt, STAGE_CAP);
    for (int i = tid; i < lim; i += 512)            // dense 4B copy-out
        csr[s + i] = cst[i];
}

// t1 = fp16(X @ W1) + packed dis.  8 lanes per node: each lane owns 16 of the
// 128 inputs (4 coalesced float4 loads), W1 transposed in LDS (stride 132),
// 192 independent FMAs per lane, then 3-step shuffle reduction.
__global__ void lin1_kernel(const float* __restrict__ X, const float* __restrict__ W1,
                            const float* __restrict__ dis, uint4* __restrict__ t1, int n) {
    __shared__ float w1t[12 * WSTR];
    int tid = threadIdx.x;
    for (int i = tid; i < 128 * 12; i += 256) {
        int k = i / 12, o = i - k * 12;
        w1t[o * WSTR + k] = W1[i];
    }
    __syncthreads();
    int gt   = blockIdx.x * 256 + tid;
    int node = gt >> 3;
    int sub  = gt & 7;
    if (node >= n) return;

    const float4* xp = (const float4*)(X + (size_t)node * 128 + sub * 16);
    float4 x0 = xp[0], x1 = xp[1], x2 = xp[2], x3 = xp[3];

    float res[12];
#pragma unroll
    for (int o = 0; o < 12; o++) {
        const float4* wp = (const float4*)(w1t + o * WSTR + sub * 16);
        float4 w0 = wp[0], w1v = wp[1], w2 = wp[2], w3 = wp[3];
        float s;
        s  = x0.x * w0.x + x0.y * w0.y + x0.z * w0.z + x0.w * w0.w;
        s += x1.x * w1v.x + x1.y * w1v.y + x1.z * w1v.z + x1.w * w1v.w;
        s += x2.x * w2.x + x2.y * w2.y + x2.z * w2.z + x2.w * w2.w;
        s += x3.x * w3.x + x3.y * w3.y + x3.z * w3.z + x3.w * w3.w;
        res[o] = s;
    }
#pragma unroll
    for (int o = 0; o < 12; o++) {
        res[o] += __shfl_xor(res[o], 1, 64);
        res[o] += __shfl_xor(res[o], 2, 64);
        res[o] += __shfl_xor(res[o], 4, 64);
    }
    if (sub == 0) {
        h8 a, b;
#pragma unroll
        for (int o = 0; o < 8; o++) a[o] = (_Float16)res[o];
#pragma unroll
        for (int o = 0; o < 4; o++) b[o] = (_Float16)res[8 + o];
#pragma unroll
        for (int o = 4; o < 8; o++) b[o] = (_Float16)0.f;
        uint4 ua = __builtin_bit_cast(uint4, a);
        uint4 ub = __builtin_bit_cast(uint4, b);
        ub.z = __float_as_uint(dis[node]);
        ub.w = 0u;
        uint4* dst = t1 + (size_t)node * 2;
        dst[0] = ua;
        dst[1] = ub;
    }
}

// Pull aggregation, 8 lanes per node, 32 nodes per 256-thr block.
// (R6 structure, R8 4B records): block's contiguous csr segment is DMA-staged
// into LDS (12KB now); inner loop reads packed records from LDS, only the
// feature gather stays on VMEM (dual chains in flight).
template <int DIN, int ROWW, int DOUT, bool LAST>
__global__ __launch_bounds__(256)
void agg_kernel(const int* __restrict__ row_ptr, const unsigned* __restrict__ csr,
                const uint4* __restrict__ hin,
                const float* __restrict__ b_this, const float* __restrict__ W_next,
                const float* __restrict__ b_next, void* __restrict__ hout_v, int n) {
    __shared__ unsigned scsr[SCAP];
    int tid = threadIdx.x;
    int nodeBase = blockIdx.x << 5;          // 32 nodes per block
    int node = nodeBase + (tid >> 3);
    int sub  = tid & 7;
    int endNode  = min(nodeBase + 32, n);
    int blkStart = row_ptr[nodeBase];
    int blkEnd   = row_ptr[endNode];
    int blkCnt   = blkEnd - blkStart;
    int lim = min(blkCnt, SCAP);
    {   // DMA stage: 4 waves x 64 lanes x 16 B = 1024 recs/iter (4B recs)
        int wave = tid >> 6, lane = tid & 63;
        int iters = (lim + 1023) >> 10;      // rounds up; over-read inside partA
        for (int it = 0; it < iters; ++it) {
            int recBase = (it << 10) + (wave << 8);        // wave-uniform
            const unsigned* src = csr + blkStart + recBase + (lane << 2);
            GLOAD_LDS16(src, (char*)scsr + ((size_t)recBase << 2));
        }
    }
    asm volatile("s_waitcnt vmcnt(0)" ::: "memory");
    __syncthreads();

    if (node >= n) return;                   // after barrier: safe
    int start = row_ptr[node];
    int end   = row_ptr[node + 1];
    float acc[DIN], acc2[DIN];
#pragma unroll
    for (int d = 0; d < DIN; d++) { acc[d] = 0.f; acc2[d] = 0.f; }

    auto body = [&](unsigned r, float* a_) {
        int src  = (int)(r & 0x1FFFFu);
        float wq = rec_w(r);
        const uint4* hr = hin + (size_t)src * ROWW;
        if constexpr (DIN == 12) {
            uint4 ua = hr[0], ub = hr[1];
            float norm = wq * __uint_as_float(ub.z);
            h8 a = __builtin_bit_cast(h8, ua);
            h8 b = __builtin_bit_cast(h8, ub);
#pragma unroll
            for (int d = 0; d < 8; d++) a_[d] += norm * (float)a[d];
#pragma unroll
            for (int d = 0; d < 4; d++) a_[8 + d] += norm * (float)b[d];
        } else if constexpr (DIN == 6) {
            uint4 u = hr[0];
            float norm = wq * __uint_as_float(u.w);
            h8 a = __builtin_bit_cast(h8, u);
#pragma unroll
            for (int d = 0; d < 6; d++) a_[d] += norm * (float)a[d];
        } else {  // DIN == 3
            uint4 u = hr[0];
            float norm = wq * __uint_as_float(u.z);
            h8 a = __builtin_bit_cast(h8, u);
#pragma unroll
            for (int d = 0; d < 3; d++) a_[d] += norm * (float)a[d];
        }
    };

    if (blkCnt <= SCAP) {                    // block-uniform fast path
        int ls = start - blkStart;
        int le = end - blkStart;
        int e = ls + sub;
        for (; e + 8 < le; e += 16) {        // dual independent gather chains
            unsigned r0 = scsr[e];
            unsigned r1 = scsr[e + 8];
            body(r0, acc);
            body(r1, acc2);
        }
        if (e < le) body(scsr[e], acc);
    } else {                                 // overflow fallback: global reads
        int e = start + sub;
        for (; e + 8 < end; e += 16) {
            unsigned r0 = csr[e];
            unsigned r1 = csr[e + 8];
            body(r0, acc);
            body(r1, acc2);
        }
        if (e < end) body(csr[e], acc);
    }

#pragma unroll
    for (int d = 0; d < DIN; d++) {
        acc[d] += acc2[d];
        acc[d] += __shfl_xor(acc[d], 1, 64);
        acc[d] += __shfl_xor(acc[d], 2, 64);
        acc[d] += __shfl_xor(acc[d], 4, 64);
    }

    if (sub == 0) {
        const uint4* hn = hin + (size_t)node * ROWW;
        float v[DIN];
        float dn;
        if constexpr (DIN == 12) {
            uint4 ua = hn[0], ub = hn[1];
            dn = __uint_as_float(ub.z);
            float s2 = dn * dn;
            h8 a = __builtin_bit_cast(h8, ua);
            h8 b = __builtin_bit_cast(h8, ub);
#pragma unroll
            for (int d = 0; d < 8; d++) v[d] = fmaxf(acc[d] + s2 * (float)a[d] + b_this[d], 0.f);
#pragma unroll
            for (int d = 0; d < 4; d++) v[8 + d] = fmaxf(acc[8 + d] + s2 * (float)b[d] + b_this[8 + d], 0.f);
        } else if constexpr (DIN == 6) {
            uint4 u = hn[0];
            dn = __uint_as_float(u.w);
            float s2 = dn * dn;
            h8 a = __builtin_bit_cast(h8, u);
#pragma unroll
            for (int d = 0; d < 6; d++) v[d] = fmaxf(acc[d] + s2 * (float)a[d] + b_this[d], 0.f);
        } else {
            uint4 u = hn[0];
            dn = __uint_as_float(u.z);
            float s2 = dn * dn;
            h8 a = __builtin_bit_cast(h8, u);
#pragma unroll
            for (int d = 0; d < 3; d++) v[d] = fmaxf(acc[d] + s2 * (float)a[d] + b_this[d], 0.f);
        }
        if constexpr (!LAST) {
            float o[DOUT];
#pragma unroll
            for (int oo = 0; oo < DOUT; oo++) {
                float z = 0.f;
#pragma unroll
                for (int d = 0; d < DIN; d++) z += v[d] * W_next[d * DOUT + oo];
                o[oo] = z;
            }
            h8 w;
#pragma unroll
            for (int oo = 0; oo < 8; oo++) w[oo] = (_Float16)0.f;
#pragma unroll
            for (int oo = 0; oo < DOUT; oo++) w[oo] = (_Float16)o[oo];
            uint4 uw = __builtin_bit_cast(uint4, w);
            if constexpr (DOUT == 6) uw.w = __float_as_uint(dn);
            else                     uw.z = __float_as_uint(dn);
            ((uint4*)hout_v)[node] = uw;
        } else {
            float z = b_next[0];
#pragma unroll
            for (int d = 0; d < DIN; d++) z += v[d] * W_next[d];
            ((float*)hout_v)[node] = 1.0f / (1.0f + expf(-z));
        }
    }
}

// ---------------------------------------------------------------------------
extern "C" void kernel_launch(void* const* d_in, const int* in_sizes, int n_in,
                              void* d_out, int out_size, void* d_ws, size_t ws_size,
                              hipStream_t stream) {
    const float* X  = (const float*)d_in[0];
    const int*   ei = (const int*)d_in[1];
    const float* ew = (const float*)d_in[2];
    const float* W1 = (const float*)d_in[3];
    const float* b1 = (const float*)d_in[4];
    const float* W2 = (const float*)d_in[5];
    const float* b2 = (const float*)d_in[6];
    const float* W3 = (const float*)d_in[7];
    const float* b3 = (const float*)d_in[8];
    const float* Wl = (const float*)d_in[9];
    const float* bl = (const float*)d_in[10];
    float* out = (float*)d_out;

    const int N = in_sizes[0] / 128;
    const int E = in_sizes[1] / 2;
    const int* row = ei;
    const int* col = ei + E;
    const int nfine   = (N + RANGE - 1) >> RSHIFT;
    const int ncoarse = (N + CRANGE - 1) >> CSHIFT;

    char* ws = (char*)d_ws;
    size_t off = 0;
    auto carve = [&](size_t bytes) -> void* {
        void* p = ws + off;
        off += (bytes + 255) & ~(size_t)255;
        return p;
    };
    int*   fcnt    = (int*)  carve((size_t)MAXBUCK * PAD * 4);
    int*   fcur    = (int*)  carve((size_t)MAXBUCK * PAD * 4);
    int*   ccur    = (int*)  carve((size_t)MAXC * PAD * 4);
    int*   cbase   = (int*)  carve((size_t)(MAXC + 1) * 4);
    int*   fbase   = (int*)  carve((size_t)(MAXBUCK + 1) * 4);
    int*   row_ptr = (int*)  carve((size_t)(N + 1) * 4);
    float* dis     = (float*)carve((size_t)N * 4);
    uint2* partA   = (uint2*)carve((size_t)E * 8);
    uint2* partB   = (uint2*)carve((size_t)(E + STAGE_CAP) * 8);  // pad kept (harmless)
    // csr (4B recs) reuses partA (dead after fine scatter); t1/t2/t3 reuse partB
    unsigned* csr = (unsigned*)partA;
    uint4* t1  = (uint4*)partB;                 // N rows x 2 uint4 (32 B)
    uint4* t2  = t1 + (size_t)N * 2;            // N rows x 1 uint4 (16 B)
    uint4* t3  = t2 + (size_t)N;                // N rows x 1 uint4 (16 B)
    (void)ws_size; (void)n_in; (void)out_size;

    const int bCnt = (E + CH_CNT - 1) / CH_CNT;
    const int bSc  = (E + CH_SC - 1) / CH_SC;       // 1563 scatter blocks
    const int bL   = ((size_t)N * 8 + 255) / 256;   // lin1: 8 lanes per node
    const int bA   = (N + 31) / 32;                 // agg: 32 nodes per block

    zero_pad_kernel<<<(nfine + 255) / 256, 256, 0, stream>>>(fcnt, nfine);
    count_kernel<<<bCnt, 256, 0, stream>>>(col, fcnt, nfine, E);
    scan_kernel<<<1, 1024, 0, stream>>>(fcnt, fbase, fcur, cbase, ccur, row_ptr,
                                        nfine, ncoarse, N, E);
    coarse_scatter_kernel<<<bSc, 256, 0, stream>>>(row, col, ew, ccur, partA, ncoarse, E);
    fine_scatter_kernel<<<bSc, 256, 0, stream>>>(partA, cbase, fcur, partB, nfine, ncoarse, E);
    bucket_csr_kernel<<<nfine, 512, 0, stream>>>(partB, fbase, row_ptr, dis, csr, N);
    lin1_kernel<<<bL, 256, 0, stream>>>(X, W1, dis, t1, N);
    agg_kernel<12, 2, 6, false><<<bA, 256, 0, stream>>>(row_ptr, csr, t1, b1, W2, nullptr, t2, N);
    agg_kernel< 6, 1, 3, false><<<bA, 256, 0, stream>>>(row_ptr, csr, t2, b2, W3, nullptr, t3, N);
    agg_kernel< 3, 1, 1, true ><<<bA, 256, 0, stream>>>(row_ptr, csr, t3, b3, Wl, bl, out, N);
}